// Round 3
// baseline (1572170.605 us; speedup 1.0000x reference)
//
#include <hip/hip_runtime.h>
#include <cstddef>

#define S_LEN 256
#define H_DIM 512
#define B_SZ  4

__device__ __forceinline__ float sigf(float x) { return 1.0f / (1.0f + expf(-x)); }

// ---- sc0 (GLC) helpers: bypass L1, hit the XCD-local L2 (coherent within XCD) ----
__device__ __forceinline__ void st_sc0(float* p, float v) {
  asm volatile("global_store_dword %0, %1, off sc0" :: "v"(p), "v"(v) : "memory");
}
__device__ __forceinline__ void st_sc0_i(int* p, int v) {
  asm volatile("global_store_dword %0, %1, off sc0" :: "v"(p), "v"(v) : "memory");
}
__device__ __forceinline__ float2 ld2_sc0(const float* p) {
  float2 v;
  asm volatile("global_load_dwordx2 %0, %1, off sc0\n\ts_waitcnt vmcnt(0)"
               : "=v"(v) : "v"(p) : "memory");
  return v;
}
__device__ __forceinline__ int ldi_sc0(const int* p) {
  int v;
  asm volatile("global_load_dword %0, %1, off sc0\n\ts_waitcnt vmcnt(0)"
               : "=v"(v) : "v"(p) : "memory");
  return v;
}
__device__ __forceinline__ void wait_vm0() {
  asm volatile("s_waitcnt vmcnt(0)" ::: "memory");
}

// ---------------- zero init ----------------
__global__ void zero_kernel(float* __restrict__ p, int n4) {
  int i = blockIdx.x * blockDim.x + threadIdx.x;
  if (i < n4) ((float4*)p)[i] = make_float4(0.f, 0.f, 0.f, 0.f);
}

__global__ void init_winner(int* a, int* b, int* c) {
  *a = -1; *b = -1; *c = -1;
}

// ---------------- embedding + DyT ----------------
__global__ __launch_bounds__(128)
void embed_dyt(const int* __restrict__ idx, const float* __restrict__ E,
               const float* __restrict__ alpha_p, const float* __restrict__ gamma,
               const float* __restrict__ beta, float* __restrict__ out) {
  const int row = blockIdx.x;
  const int t4  = threadIdx.x * 4;
  const int id  = idx[row];
  const float al = alpha_p[0];
  float4 e = make_float4(0.f, 0.f, 0.f, 0.f);
  if (id != 0) e = *(const float4*)(E + (size_t)id * H_DIM + t4);
  const float4 g = *(const float4*)(gamma + t4);
  const float4 b = *(const float4*)(beta + t4);
  float4 o;
  o.x = g.x * tanhf(al * e.x) + b.x;
  o.y = g.y * tanhf(al * e.y) + b.y;
  o.z = g.z * tanhf(al * e.z) + b.z;
  o.w = g.w * tanhf(al * e.w) + b.w;
  *(float4*)(out + (size_t)row * H_DIM + t4) = o;
}

// ---------------- GEMM: C[M,N] = A[M,K] @ W[N,K]^T + bias, optional DyT epilogue ----
template<int EPI>
__global__ __launch_bounds__(256)
void gemm_nt(const float* __restrict__ A, const float* __restrict__ W,
             const float* __restrict__ bias, float* __restrict__ C,
             int N, int K,
             const float* __restrict__ alpha_p, const float* __restrict__ gamma,
             const float* __restrict__ beta, const float* __restrict__ residual) {
  __shared__ float As[8][132];
  __shared__ float Ws[8][132];
  const int bm = blockIdx.x * 128;
  const int bn = blockIdx.y * 128;
  const int tid = threadIdx.x;
  const int tx = tid & 15, ty = tid >> 4;
  float acc[8][8] = {};
  const int i4 = tid * 4;
  const int lm = i4 >> 3;
  const int lk = i4 & 7;
  const float* Arow = A + (size_t)(bm + lm) * K + lk;
  const float* Wrow = W + (size_t)(bn + lm) * K + lk;

  for (int k0 = 0; k0 < K; k0 += 8) {
    float4 va = *(const float4*)(Arow + k0);
    float4 vw = *(const float4*)(Wrow + k0);
    As[lk + 0][lm] = va.x; As[lk + 1][lm] = va.y; As[lk + 2][lm] = va.z; As[lk + 3][lm] = va.w;
    Ws[lk + 0][lm] = vw.x; Ws[lk + 1][lm] = vw.y; Ws[lk + 2][lm] = vw.z; Ws[lk + 3][lm] = vw.w;
    __syncthreads();
#pragma unroll
    for (int kk = 0; kk < 8; ++kk) {
      float a[8], w[8];
      *(float4*)(a)     = *(const float4*)&As[kk][ty * 4];
      *(float4*)(a + 4) = *(const float4*)&As[kk][64 + ty * 4];
      *(float4*)(w)     = *(const float4*)&Ws[kk][tx * 4];
      *(float4*)(w + 4) = *(const float4*)&Ws[kk][64 + tx * 4];
#pragma unroll
      for (int ii = 0; ii < 8; ++ii)
#pragma unroll
        for (int jj = 0; jj < 8; ++jj)
          acc[ii][jj] += a[ii] * w[jj];
    }
    __syncthreads();
  }

  float al = 0.f;
  if (EPI == 1) al = alpha_p[0];
#pragma unroll
  for (int ii = 0; ii < 8; ++ii) {
    const int row = bm + ((ii < 4) ? (ty * 4 + ii) : (60 + ty * 4 + ii));
#pragma unroll
    for (int hf = 0; hf < 2; ++hf) {
      const int ncol = bn + hf * 64 + tx * 4;
      float4 v;
      v.x = acc[ii][hf * 4 + 0]; v.y = acc[ii][hf * 4 + 1];
      v.z = acc[ii][hf * 4 + 2]; v.w = acc[ii][hf * 4 + 3];
      const float4 bb = *(const float4*)(bias + ncol);
      v.x += bb.x; v.y += bb.y; v.z += bb.z; v.w += bb.w;
      if (EPI == 1) {
        if (residual) {
          const float4 r = *(const float4*)(residual + (size_t)row * N + ncol);
          v.x += r.x; v.y += r.y; v.z += r.z; v.w += r.w;
        }
        const float4 gg = *(const float4*)(gamma + ncol);
        const float4 be = *(const float4*)(beta + ncol);
        v.x = gg.x * tanhf(al * v.x) + be.x;
        v.y = gg.y * tanhf(al * v.y) + be.y;
        v.z = gg.z * tanhf(al * v.z) + be.z;
        v.w = gg.w * tanhf(al * v.w) + be.w;
      }
      *(float4*)(C + (size_t)row * N + ncol) = v;
    }
  }
}

// ---------------- XCD-local persistent SLSTM ----------------
struct PArgs {
  const float* xg;       // [(b*S+t)*stride + grow]
  const float* Whh;      // [2048,512]
  const float* bhh;      // [2048]
  const float* c_init;   // [4,512]
  const float* h_init;   // [4,512]
  float* c_fin;          // [4,512] or nullptr
  float* ring;           // [2][4*512]
  int*   flags;          // [16]
  float* spk;            // [B*S,512] or nullptr
  const float* thr;      // [512]
  int xg_stride;
  int nsteps;
};

// NROLE WGs (16 per layer-group) are claimed on ONE XCD; h exchanged via that
// XCD's L2 with sc0 ops. Role r owns h cols [32r, 32r+32).
template<int NROLE>
__global__ __launch_bounds__(1024)
void slstm_xcd(int* cnt, int* winner, PArgs A0, PArgs A1) {
  __shared__ int s_role;
  const int tid = threadIdx.x;
  if (tid == 0) {
    unsigned xcd;
    asm volatile("s_getreg_b32 %0, hwreg(HW_REG_XCC_ID)" : "=s"(xcd));
    xcd &= 7u;
    int role = -1;
    int slot = atomicAdd(cnt + xcd, 1);
    if (slot < NROLE) {
      if (slot == NROLE - 1) atomicCAS(winner, -1, (int)xcd);
      int w = -1, cap = 0;
      do {
        w = __hip_atomic_load(winner, __ATOMIC_RELAXED, __HIP_MEMORY_SCOPE_AGENT);
      } while (w == -1 && ++cap < 8000000);
      if (w == (int)xcd) role = slot;
    }
    s_role = role;
  }
  __syncthreads();
  const int role = s_role;
  if (role < 0) return;
  const PArgs P = (role < 16) ? A0 : A1;
  const int rr = role & 15;

  const int lr = tid >> 3, kc = tid & 7;     // 128 gate rows x 8 k-chunks
  const int q = lr >> 5, ci = lr & 31;       // gate q, local col ci
  const int grow = q * H_DIM + rr * 32 + ci;

  // weights resident in VGPRs: 16 x float4 per thread
  float4 w[16];
  {
    const float* wrow = P.Whh + (size_t)grow * H_DIM + kc * 4;
#pragma unroll
    for (int it = 0; it < 16; ++it) w[it] = *(const float4*)(wrow + it * 32);
  }
  const float bb = P.bhh[grow];
  const float* xgp = P.xg + grow;

  __shared__ float hs[4 * H_DIM];
  __shared__ float gred[128][4];
  __shared__ float cst[128];
  if (tid < 128) {
    const int b = tid & 3, cc = tid >> 2;
    cst[tid] = P.c_init[b * H_DIM + rr * 32 + cc];
  }

  int pollcap = 0;
  for (int t = 0; t < P.nsteps; ++t) {
    // xg prefetch (independent of h)
    float xgv0 = 0.f, xgv1 = 0.f, xgv2 = 0.f, xgv3 = 0.f;
    if (kc == 0) {
      xgv0 = xgp[(size_t)(0 * S_LEN + t) * P.xg_stride];
      xgv1 = xgp[(size_t)(1 * S_LEN + t) * P.xg_stride];
      xgv2 = xgp[(size_t)(2 * S_LEN + t) * P.xg_stride];
      xgv3 = xgp[(size_t)(3 * S_LEN + t) * P.xg_stride];
    }
    const float* hsrc = (t == 0) ? P.h_init : (P.ring + (size_t)(t & 1) * 2048);
    if (t > 0 && tid < 64) {
      const int* fp = P.flags + (tid & 15);
      while (true) {
        int v = ldi_sc0(fp);
        if (__all(v >= t)) break;
        if (++pollcap > 6000000) break;   // safety: never hang
      }
    }
    __syncthreads();
    {
      float2 hv = ld2_sc0(hsrc + tid * 2);
      *(float2*)&hs[tid * 2] = hv;
    }
    __syncthreads();

    float a0 = 0.f, a1 = 0.f, a2 = 0.f, a3 = 0.f;
#pragma unroll
    for (int it = 0; it < 16; ++it) {
      const int k = it * 32 + kc * 4;
      const float4 wv = w[it];
      const float4 h0 = *(const float4*)&hs[0 * H_DIM + k];
      const float4 h1 = *(const float4*)&hs[1 * H_DIM + k];
      const float4 h2 = *(const float4*)&hs[2 * H_DIM + k];
      const float4 h3 = *(const float4*)&hs[3 * H_DIM + k];
      a0 += wv.x * h0.x + wv.y * h0.y + wv.z * h0.z + wv.w * h0.w;
      a1 += wv.x * h1.x + wv.y * h1.y + wv.z * h1.z + wv.w * h1.w;
      a2 += wv.x * h2.x + wv.y * h2.y + wv.z * h2.z + wv.w * h2.w;
      a3 += wv.x * h3.x + wv.y * h3.y + wv.z * h3.z + wv.w * h3.w;
    }
#pragma unroll
    for (int off = 1; off < 8; off <<= 1) {
      a0 += __shfl_xor(a0, off);
      a1 += __shfl_xor(a1, off);
      a2 += __shfl_xor(a2, off);
      a3 += __shfl_xor(a3, off);
    }
    if (kc == 0) {
      gred[lr][0] = a0 + xgv0 + bb;
      gred[lr][1] = a1 + xgv1 + bb;
      gred[lr][2] = a2 + xgv2 + bb;
      gred[lr][3] = a3 + xgv3 + bb;
    }
    __syncthreads();

    if (tid < 128) {
      const int b = tid & 3, cc = tid >> 2;
      const int col = rr * 32 + cc;
      const float gi = gred[cc][b];
      const float gf = gred[32 + cc][b];
      const float gg = gred[64 + cc][b];
      const float go = gred[96 + cc][b];
      const float cold = cst[tid];
      const float cn = sigf(gf) * cold + sigf(gi) * tanhf(gg);
      const float hn = sigf(go) * tanhf(cn);
      cst[tid] = cn;
      st_sc0(P.ring + (size_t)((t + 1) & 1) * 2048 + b * H_DIM + col, hn);
      if (P.spk)
        P.spk[(size_t)(b * S_LEN + t) * H_DIM + col] = (hn - P.thr[col]) > 0.f ? 1.f : 0.f;
      if (P.c_fin && t == P.nsteps - 1)
        P.c_fin[b * H_DIM + col] = cn;
      wait_vm0();   // h stores ack'd by L2 before flag
    }
    __syncthreads();
    if (tid == 0) st_sc0_i(P.flags + rr, t + 1);
  }
}

extern "C" void kernel_launch(void* const* d_in, const int* in_sizes, int n_in,
                              void* d_out, int out_size, void* d_ws, size_t ws_size,
                              hipStream_t stream) {
  (void)in_sizes; (void)n_in; (void)out_size; (void)ws_size;
  const int*   src       = (const int*)d_in[0];
  const int*   tgt       = (const int*)d_in[1];
  const float* emb_enc   = (const float*)d_in[2];
  const float* enc_alpha = (const float*)d_in[3];
  const float* enc_gamma = (const float*)d_in[4];
  const float* enc_beta  = (const float*)d_in[5];
  const float* enc_Wih   = (const float*)d_in[6];
  const float* enc_Whh   = (const float*)d_in[7];
  const float* enc_bih   = (const float*)d_in[8];
  const float* enc_bhh   = (const float*)d_in[9];
  const float* emb_dec   = (const float*)d_in[11];
  const float* dec_alpha = (const float*)d_in[12];
  const float* dec_gamma = (const float*)d_in[13];
  const float* dec_beta  = (const float*)d_in[14];
  const float* dec_Wih   = (const float*)d_in[15];
  const float* dec_Whh   = (const float*)d_in[16];
  const float* dec_bih   = (const float*)d_in[17];
  const float* dec_bhh   = (const float*)d_in[18];
  const float* dec_thr   = (const float*)d_in[19];
  const float* dec_fc_W  = (const float*)d_in[20];
  const float* dec_fc_b  = (const float*)d_in[21];
  const float* dyt_alpha = (const float*)d_in[22];
  const float* dyt_gamma = (const float*)d_in[23];
  const float* dyt_beta  = (const float*)d_in[24];
  const float* out_W     = (const float*)d_in[25];
  const float* out_b     = (const float*)d_in[26];
  float* out = (float*)d_out;

  float* ws     = (float*)d_ws;
  float* src_e  = ws;                       // [1024,512]
  float* dec_x0 = ws + 524288;
  float* dec_x1 = ws + 1048576;
  float* xg_enc = ws + 1572864;             // [1024,4096]
  float* xg_dec = ws + 5767168;             // [1024,2048]
  float* spk    = ws + 7864320;             // [1024,512]
  float* st     = ws + 8388608;             // control/state block
  float* zbuf    = st;                      // [2048] zeros
  float* cfin    = st + 2048;               // 2 x [2048]
  float* ring_e0 = st + 6144;               // [2][2048]
  float* ring_e1 = st + 10240;
  float* ring_d0 = st + 14336;
  float* ring_d1 = st + 18432;
  int*   ipart   = (int*)(st + 22528);
  int* flags_e0 = ipart;
  int* flags_e1 = ipart + 16;
  int* flags_d0 = ipart + 32;
  int* flags_d1 = ipart + 48;
  int* cnt_enc  = ipart + 64;
  int* win_enc  = ipart + 72;
  int* cnt_d0   = ipart + 80;
  int* win_d0   = ipart + 88;
  int* cnt_d1   = ipart + 96;
  int* win_d1   = ipart + 104;

  zero_kernel<<<23, 256, 0, stream>>>(st, 5696);   // zbuf..ctrl region
  init_winner<<<1, 1, 0, stream>>>(win_enc, win_d0, win_d1);
  embed_dyt<<<1024, 128, 0, stream>>>(src, emb_enc, enc_alpha, enc_gamma, enc_beta, src_e);
  embed_dyt<<<1024, 128, 0, stream>>>(tgt, emb_dec, dec_alpha, dec_gamma, dec_beta, dec_x0);

  gemm_nt<0><<<dim3(8, 32), 256, 0, stream>>>(src_e, enc_Wih, enc_bih, xg_enc, 4096, 512,
                                              nullptr, nullptr, nullptr, nullptr);

  // Encoder: both layers as role-groups {0-15}, {16-31} on one claimed XCD
  PArgs E0, E1;
  E0.xg = xg_enc;        E0.Whh = enc_Whh;            E0.bhh = enc_bhh;
  E0.c_init = zbuf;      E0.h_init = zbuf;            E0.c_fin = cfin;
  E0.ring = ring_e0;     E0.flags = flags_e0;         E0.spk = nullptr;
  E0.thr = nullptr;      E0.xg_stride = 4096;         E0.nsteps = 256;
  E1 = E0;
  E1.xg = xg_enc + 2048; E1.Whh = enc_Whh + 1048576;  E1.bhh = enc_bhh + 2048;
  E1.c_fin = cfin + 2048;
  E1.ring = ring_e1;     E1.flags = flags_e1;
  slstm_xcd<32><<<256, 1024, 0, stream>>>(cnt_enc, win_enc, E0, E1);
  // final h(256) of enc layer l = ring_e{l} parity 0; final c in cfin[l]

  const float* xin = dec_x0;
  float* xout = dec_x1;
  for (int l = 0; l < 2; ++l) {
    gemm_nt<0><<<dim3(8, 16), 256, 0, stream>>>(xin, dec_Wih + (size_t)l * 1048576,
                                                dec_bih + l * 2048, xg_dec, 2048, 512,
                                                nullptr, nullptr, nullptr, nullptr);
    PArgs D;
    D.xg = xg_dec;                 D.Whh = dec_Whh + (size_t)l * 1048576;
    D.bhh = dec_bhh + l * 2048;
    D.c_init = cfin + l * 2048;    D.h_init = (l == 0) ? ring_e0 : ring_e1;
    D.c_fin = nullptr;
    D.ring = (l == 0) ? ring_d0 : ring_d1;
    D.flags = (l == 0) ? flags_d0 : flags_d1;
    D.spk = spk;                   D.thr = dec_thr + l * 512;
    D.xg_stride = 2048;            D.nsteps = 256;
    slstm_xcd<16><<<128, 1024, 0, stream>>>((l == 0) ? cnt_d0 : cnt_d1,
                                            (l == 0) ? win_d0 : win_d1, D, D);

    gemm_nt<1><<<dim3(8, 4), 256, 0, stream>>>(spk, dec_fc_W + (size_t)l * 262144,
                                               dec_fc_b + l * 512, xout, 512, 512,
                                               dyt_alpha + l, dyt_gamma + l * 512,
                                               dyt_beta + l * 512,
                                               (l > 0) ? xin : nullptr);
    const float* tmp = xin; xin = xout; xout = (float*)tmp;
  }

  gemm_nt<0><<<dim3(8, 250), 256, 0, stream>>>(xin, out_W, out_b, out, 32000, 512,
                                               nullptr, nullptr, nullptr, nullptr);
}

// Round 4
// 2939.898 us; speedup vs baseline: 534.7705x; 534.7705x over previous
//
#include <hip/hip_runtime.h>
#include <cstddef>

#define S_LEN 256
#define H_DIM 512
#define B_SZ  4

__device__ __forceinline__ float sigf(float x) { return 1.0f / (1.0f + expf(-x)); }

// ---------------- zero init ----------------
__global__ void zero_kernel(float* __restrict__ p, int n4) {
  int i = blockIdx.x * blockDim.x + threadIdx.x;
  if (i < n4) ((float4*)p)[i] = make_float4(0.f, 0.f, 0.f, 0.f);
}

// ---------------- embedding + DyT ----------------
__global__ __launch_bounds__(128)
void embed_dyt(const int* __restrict__ idx, const float* __restrict__ E,
               const float* __restrict__ alpha_p, const float* __restrict__ gamma,
               const float* __restrict__ beta, float* __restrict__ out) {
  const int row = blockIdx.x;
  const int t4  = threadIdx.x * 4;
  const int id  = idx[row];
  const float al = alpha_p[0];
  float4 e = make_float4(0.f, 0.f, 0.f, 0.f);
  if (id != 0) e = *(const float4*)(E + (size_t)id * H_DIM + t4);
  const float4 g = *(const float4*)(gamma + t4);
  const float4 b = *(const float4*)(beta + t4);
  float4 o;
  o.x = g.x * tanhf(al * e.x) + b.x;
  o.y = g.y * tanhf(al * e.y) + b.y;
  o.z = g.z * tanhf(al * e.z) + b.z;
  o.w = g.w * tanhf(al * e.w) + b.w;
  *(float4*)(out + (size_t)row * H_DIM + t4) = o;
}

// ---------------- GEMM: C[M,N] = A[M,K] @ W[N,K]^T + bias ----------------
template<int EPI>
__global__ __launch_bounds__(256)
void gemm_nt(const float* __restrict__ A, const float* __restrict__ W,
             const float* __restrict__ bias, float* __restrict__ C,
             int N, int K) {
  __shared__ float As[8][132];
  __shared__ float Ws[8][132];
  const int bm = blockIdx.x * 128;
  const int bn = blockIdx.y * 128;
  const int tid = threadIdx.x;
  const int tx = tid & 15, ty = tid >> 4;
  float acc[8][8] = {};
  const int i4 = tid * 4;
  const int lm = i4 >> 3;
  const int lk = i4 & 7;
  const float* Arow = A + (size_t)(bm + lm) * K + lk;
  const float* Wrow = W + (size_t)(bn + lm) * K + lk;

  for (int k0 = 0; k0 < K; k0 += 8) {
    float4 va = *(const float4*)(Arow + k0);
    float4 vw = *(const float4*)(Wrow + k0);
    As[lk + 0][lm] = va.x; As[lk + 1][lm] = va.y; As[lk + 2][lm] = va.z; As[lk + 3][lm] = va.w;
    Ws[lk + 0][lm] = vw.x; Ws[lk + 1][lm] = vw.y; Ws[lk + 2][lm] = vw.z; Ws[lk + 3][lm] = vw.w;
    __syncthreads();
#pragma unroll
    for (int kk = 0; kk < 8; ++kk) {
      float a[8], w[8];
      *(float4*)(a)     = *(const float4*)&As[kk][ty * 4];
      *(float4*)(a + 4) = *(const float4*)&As[kk][64 + ty * 4];
      *(float4*)(w)     = *(const float4*)&Ws[kk][tx * 4];
      *(float4*)(w + 4) = *(const float4*)&Ws[kk][64 + tx * 4];
#pragma unroll
      for (int ii = 0; ii < 8; ++ii)
#pragma unroll
        for (int jj = 0; jj < 8; ++jj)
          acc[ii][jj] += a[ii] * w[jj];
    }
    __syncthreads();
  }

#pragma unroll
  for (int ii = 0; ii < 8; ++ii) {
    const int row = bm + ((ii < 4) ? (ty * 4 + ii) : (60 + ty * 4 + ii));
#pragma unroll
    for (int hf = 0; hf < 2; ++hf) {
      const int ncol = bn + hf * 64 + tx * 4;
      float4 v;
      v.x = acc[ii][hf * 4 + 0]; v.y = acc[ii][hf * 4 + 1];
      v.z = acc[ii][hf * 4 + 2]; v.w = acc[ii][hf * 4 + 3];
      const float4 bb = *(const float4*)(bias + ncol);
      v.x += bb.x; v.y += bb.y; v.z += bb.z; v.w += bb.w;
      *(float4*)(C + (size_t)row * N + ncol) = v;
    }
  }
}

// ---------------- encoder per-step kernel (r1-proven) ----------------
struct StepInst {
  const float* xg;
  const float* Whh;
  const float* bhh;
  float* c;
  const float* h_in;
  float* h_out;
  int xg_stride;
};

__global__ __launch_bounds__(256)
void slstm_step(StepInst I0, StepInst I1, int t) {
  StepInst I = (blockIdx.x < 64) ? I0 : I1;
  const int blk = blockIdx.x & 63;
  const int c0 = blk * 8;
  __shared__ float hs[4 * H_DIM];
  __shared__ float gred[32][4];
  const int tid = threadIdx.x;
  {
    const float4* s4 = (const float4*)I.h_in;
    float4* d4 = (float4*)hs;
    d4[tid] = s4[tid];
    d4[tid + 256] = s4[tid + 256];
  }
  __syncthreads();
  const int lr = tid >> 3, kc = tid & 7;
  const int q = lr >> 3, ci = lr & 7;
  const int grow = q * H_DIM + c0 + ci;
  const float* wrow = I.Whh + (size_t)grow * H_DIM;
  float a0 = 0.f, a1 = 0.f, a2 = 0.f, a3 = 0.f;
#pragma unroll
  for (int it = 0; it < 16; ++it) {
    const int k = it * 32 + kc * 4;
    const float4 w  = *(const float4*)(wrow + k);
    const float4 h0 = *(const float4*)&hs[0 * H_DIM + k];
    const float4 h1 = *(const float4*)&hs[1 * H_DIM + k];
    const float4 h2 = *(const float4*)&hs[2 * H_DIM + k];
    const float4 h3 = *(const float4*)&hs[3 * H_DIM + k];
    a0 += w.x * h0.x + w.y * h0.y + w.z * h0.z + w.w * h0.w;
    a1 += w.x * h1.x + w.y * h1.y + w.z * h1.z + w.w * h1.w;
    a2 += w.x * h2.x + w.y * h2.y + w.z * h2.z + w.w * h2.w;
    a3 += w.x * h3.x + w.y * h3.y + w.z * h3.z + w.w * h3.w;
  }
#pragma unroll
  for (int off = 1; off < 8; off <<= 1) {
    a0 += __shfl_xor(a0, off);
    a1 += __shfl_xor(a1, off);
    a2 += __shfl_xor(a2, off);
    a3 += __shfl_xor(a3, off);
  }
  if (kc == 0) {
    const float bb = I.bhh[grow];
    gred[lr][0] = a0 + I.xg[(size_t)(0 * S_LEN + t) * I.xg_stride + grow] + bb;
    gred[lr][1] = a1 + I.xg[(size_t)(1 * S_LEN + t) * I.xg_stride + grow] + bb;
    gred[lr][2] = a2 + I.xg[(size_t)(2 * S_LEN + t) * I.xg_stride + grow] + bb;
    gred[lr][3] = a3 + I.xg[(size_t)(3 * S_LEN + t) * I.xg_stride + grow] + bb;
  }
  __syncthreads();
  if (tid < 32) {
    const int b = tid & 3, cc = tid >> 2;
    const int col = c0 + cc;
    const float gi = gred[cc][b];
    const float gf = gred[8 + cc][b];
    const float gg = gred[16 + cc][b];
    const float go = gred[24 + cc][b];
    const float cold = I.c[b * H_DIM + col];
    const float cn = sigf(gf) * cold + sigf(gi) * tanhf(gg);
    const float hn = sigf(go) * tanhf(cn);
    I.c[b * H_DIM + col] = cn;
    I.h_out[b * H_DIM + col] = hn;
  }
}

// ---------------- pipelined decoder slot ----------------
struct DecArgs {
  const float* xg0;      // [1024,2048] precomputed
  float*       xg1;      // [1024,2048] role C writes, role D reads
  const float* Whh0; const float* Whh1;
  const float* bhh0; const float* bhh1;
  const float* Wih1; const float* bih1;
  const float* fc0W; const float* fc0b;
  const float* fc1W; const float* fc1b;
  const float* dyt_a;  // [2]
  const float* dyt_g;  // [2,512]
  const float* dyt_b;  // [2,512]
  const float* thr0; const float* thr1;
  float* c0; float* c1;
  const float* h0_init; const float* h1_init;
  float* ring0; float* ring1;    // [2][2048] each
  float* spk0; float* spk1;      // [1024,512]
  float* x1;  float* x2;         // [1024,512]
};

// recurrent step for one 64-WG role group (g = 0..63)
__device__ __forceinline__ void rec_step(
    int g, int t, int tid,
    const float* __restrict__ xg, const float* __restrict__ Whh,
    const float* __restrict__ bhh, const float* __restrict__ h_init,
    float* __restrict__ ring, float* __restrict__ c,
    float* __restrict__ spk, const float* __restrict__ thr,
    float* hs, float (*gred)[4]) {
  const float* h_in = (t == 0) ? h_init : (ring + (size_t)(t & 1) * 2048);
  float* h_out = ring + (size_t)((t + 1) & 1) * 2048;
  const int c0 = g * 8;
  {
    const float4* s4 = (const float4*)h_in;
    float4* d4 = (float4*)hs;
    d4[tid] = s4[tid];
    d4[tid + 256] = s4[tid + 256];
  }
  __syncthreads();
  const int lr = tid >> 3, kc = tid & 7;
  const int q = lr >> 3, ci = lr & 7;
  const int grow = q * H_DIM + c0 + ci;
  const float* wrow = Whh + (size_t)grow * H_DIM;
  float a0 = 0.f, a1 = 0.f, a2 = 0.f, a3 = 0.f;
#pragma unroll
  for (int it = 0; it < 16; ++it) {
    const int k = it * 32 + kc * 4;
    const float4 w  = *(const float4*)(wrow + k);
    const float4 h0 = *(const float4*)&hs[0 * H_DIM + k];
    const float4 h1 = *(const float4*)&hs[1 * H_DIM + k];
    const float4 h2 = *(const float4*)&hs[2 * H_DIM + k];
    const float4 h3 = *(const float4*)&hs[3 * H_DIM + k];
    a0 += w.x * h0.x + w.y * h0.y + w.z * h0.z + w.w * h0.w;
    a1 += w.x * h1.x + w.y * h1.y + w.z * h1.z + w.w * h1.w;
    a2 += w.x * h2.x + w.y * h2.y + w.z * h2.z + w.w * h2.w;
    a3 += w.x * h3.x + w.y * h3.y + w.z * h3.z + w.w * h3.w;
  }
#pragma unroll
  for (int off = 1; off < 8; off <<= 1) {
    a0 += __shfl_xor(a0, off);
    a1 += __shfl_xor(a1, off);
    a2 += __shfl_xor(a2, off);
    a3 += __shfl_xor(a3, off);
  }
  if (kc == 0) {
    const float bb = bhh[grow];
    gred[lr][0] = a0 + xg[(size_t)(0 * S_LEN + t) * 2048 + grow] + bb;
    gred[lr][1] = a1 + xg[(size_t)(1 * S_LEN + t) * 2048 + grow] + bb;
    gred[lr][2] = a2 + xg[(size_t)(2 * S_LEN + t) * 2048 + grow] + bb;
    gred[lr][3] = a3 + xg[(size_t)(3 * S_LEN + t) * 2048 + grow] + bb;
  }
  __syncthreads();
  if (tid < 32) {
    const int b = tid & 3, cc = tid >> 2;
    const int col = c0 + cc;
    const float gi = gred[cc][b];
    const float gf = gred[8 + cc][b];
    const float gg = gred[16 + cc][b];
    const float go = gred[24 + cc][b];
    const float cold = c[b * H_DIM + col];
    const float cn = sigf(gf) * cold + sigf(gi) * tanhf(gg);
    const float hn = sigf(go) * tanhf(cn);
    c[b * H_DIM + col] = cn;
    h_out[b * H_DIM + col] = hn;
    spk[(size_t)(b * S_LEN + t) * H_DIM + col] = (hn - thr[col]) > 0.f ? 1.f : 0.f;
  }
}

// stage 4x512 row-group (rows b*S+t) into LDS
__device__ __forceinline__ void stage_rows(const float* __restrict__ src, int t,
                                           int tid, float* hs) {
  float4* d4 = (float4*)hs;
  const int f0 = tid, f1 = tid + 256;   // float4 indices, 128 per row
  d4[f0] = *(const float4*)(src + (size_t)((f0 >> 7) * S_LEN + t) * H_DIM + (f0 & 127) * 4);
  d4[f1] = *(const float4*)(src + (size_t)((f1 >> 7) * S_LEN + t) * H_DIM + (f1 & 127) * 4);
}

__global__ __launch_bounds__(256)
void dec_slot(DecArgs A, int s) {
  __shared__ float hs[4 * H_DIM];
  __shared__ float gred[32][4];
  const int bid = blockIdx.x;
  const int tid = threadIdx.x;

  if (bid < 64) {
    // role A: layer0 recurrent step t = s
    const int t = s;
    if (t < 256)
      rec_step(bid, t, tid, A.xg0, A.Whh0, A.bhh0, A.h0_init, A.ring0, A.c0,
               A.spk0, A.thr0, hs, gred);
  } else if (bid < 128) {
    // role D: layer1 recurrent step t = s-3
    const int t = s - 3;
    if (t >= 0 && t < 256)
      rec_step(bid - 64, t, tid, A.xg1, A.Whh1, A.bhh1, A.h1_init, A.ring1, A.c1,
               A.spk1, A.thr1, hs, gred);
  } else if (bid < 192) {
    // role C: xg1[t] = Wih1 . x1[t] + bih1,  t = s-2
    const int t = s - 2;
    if (t >= 0 && t < 256) {
      stage_rows(A.x1, t, tid, hs);
      __syncthreads();
      const int wc = bid - 128;
      const int lr = tid >> 3, kc = tid & 7;
      const int row = wc * 32 + lr;
      const float* wrow = A.Wih1 + (size_t)row * H_DIM;
      float a0 = 0.f, a1 = 0.f, a2 = 0.f, a3 = 0.f;
#pragma unroll
      for (int it = 0; it < 16; ++it) {
        const int k = it * 32 + kc * 4;
        const float4 w  = *(const float4*)(wrow + k);
        const float4 h0 = *(const float4*)&hs[0 * H_DIM + k];
        const float4 h1 = *(const float4*)&hs[1 * H_DIM + k];
        const float4 h2 = *(const float4*)&hs[2 * H_DIM + k];
        const float4 h3 = *(const float4*)&hs[3 * H_DIM + k];
        a0 += w.x * h0.x + w.y * h0.y + w.z * h0.z + w.w * h0.w;
        a1 += w.x * h1.x + w.y * h1.y + w.z * h1.z + w.w * h1.w;
        a2 += w.x * h2.x + w.y * h2.y + w.z * h2.z + w.w * h2.w;
        a3 += w.x * h3.x + w.y * h3.y + w.z * h3.z + w.w * h3.w;
      }
#pragma unroll
      for (int off = 1; off < 8; off <<= 1) {
        a0 += __shfl_xor(a0, off);
        a1 += __shfl_xor(a1, off);
        a2 += __shfl_xor(a2, off);
        a3 += __shfl_xor(a3, off);
      }
      if (kc == 0) {
        const float bb = A.bih1[row];
        A.xg1[(size_t)(0 * S_LEN + t) * 2048 + row] = a0 + bb;
        A.xg1[(size_t)(1 * S_LEN + t) * 2048 + row] = a1 + bb;
        A.xg1[(size_t)(2 * S_LEN + t) * 2048 + row] = a2 + bb;
        A.xg1[(size_t)(3 * S_LEN + t) * 2048 + row] = a3 + bb;
      }
    }
  } else {
    // roles B/E: x = dyt(fcW . spk + fcb (+resid))
    const bool isB = (bid < 224);
    const int t = isB ? (s - 1) : (s - 4);
    if (t >= 0 && t < 256) {
      const float* spk = isB ? A.spk0 : A.spk1;
      const float* fcW = isB ? A.fc0W : A.fc1W;
      const float* fcb = isB ? A.fc0b : A.fc1b;
      const int lidx = isB ? 0 : 1;
      float* outp = isB ? A.x1 : A.x2;
      stage_rows(spk, t, tid, hs);
      __syncthreads();
      const int wb = bid - (isB ? 192 : 224);   // 0..31
      const int lr = tid >> 4, kc = tid & 15;   // 16 outs x 16 k-chunks
      const int col = wb * 16 + lr;
      const float* wrow = fcW + (size_t)col * H_DIM;
      float a0 = 0.f, a1 = 0.f, a2 = 0.f, a3 = 0.f;
#pragma unroll
      for (int it = 0; it < 8; ++it) {
        const int k = kc * 32 + it * 4;
        const float4 w  = *(const float4*)(wrow + k);
        const float4 h0 = *(const float4*)&hs[0 * H_DIM + k];
        const float4 h1 = *(const float4*)&hs[1 * H_DIM + k];
        const float4 h2 = *(const float4*)&hs[2 * H_DIM + k];
        const float4 h3 = *(const float4*)&hs[3 * H_DIM + k];
        a0 += w.x * h0.x + w.y * h0.y + w.z * h0.z + w.w * h0.w;
        a1 += w.x * h1.x + w.y * h1.y + w.z * h1.z + w.w * h1.w;
        a2 += w.x * h2.x + w.y * h2.y + w.z * h2.z + w.w * h2.w;
        a3 += w.x * h3.x + w.y * h3.y + w.z * h3.z + w.w * h3.w;
      }
#pragma unroll
      for (int off = 1; off < 16; off <<= 1) {
        a0 += __shfl_xor(a0, off);
        a1 += __shfl_xor(a1, off);
        a2 += __shfl_xor(a2, off);
        a3 += __shfl_xor(a3, off);
      }
      if (kc == 0) {
        const float al = A.dyt_a[lidx];
        const float gm = A.dyt_g[lidx * H_DIM + col];
        const float be = A.dyt_b[lidx * H_DIM + col];
        const float bb = fcb[col];
        float v[4] = {a0, a1, a2, a3};
#pragma unroll
        for (int b = 0; b < 4; ++b) {
          float y = v[b] + bb;
          if (!isB) y += A.x1[(size_t)(b * S_LEN + t) * H_DIM + col];
          outp[(size_t)(b * S_LEN + t) * H_DIM + col] = gm * tanhf(al * y) + be;
        }
      }
    }
  }
}

extern "C" void kernel_launch(void* const* d_in, const int* in_sizes, int n_in,
                              void* d_out, int out_size, void* d_ws, size_t ws_size,
                              hipStream_t stream) {
  (void)in_sizes; (void)n_in; (void)out_size; (void)ws_size;
  const int*   src       = (const int*)d_in[0];
  const int*   tgt       = (const int*)d_in[1];
  const float* emb_enc   = (const float*)d_in[2];
  const float* enc_alpha = (const float*)d_in[3];
  const float* enc_gamma = (const float*)d_in[4];
  const float* enc_beta  = (const float*)d_in[5];
  const float* enc_Wih   = (const float*)d_in[6];
  const float* enc_Whh   = (const float*)d_in[7];
  const float* enc_bih   = (const float*)d_in[8];
  const float* enc_bhh   = (const float*)d_in[9];
  const float* emb_dec   = (const float*)d_in[11];
  const float* dec_alpha = (const float*)d_in[12];
  const float* dec_gamma = (const float*)d_in[13];
  const float* dec_beta  = (const float*)d_in[14];
  const float* dec_Wih   = (const float*)d_in[15];
  const float* dec_Whh   = (const float*)d_in[16];
  const float* dec_bih   = (const float*)d_in[17];
  const float* dec_bhh   = (const float*)d_in[18];
  const float* dec_thr   = (const float*)d_in[19];
  const float* dec_fc_W  = (const float*)d_in[20];
  const float* dec_fc_b  = (const float*)d_in[21];
  const float* dyt_alpha = (const float*)d_in[22];
  const float* dyt_gamma = (const float*)d_in[23];
  const float* dyt_beta  = (const float*)d_in[24];
  const float* out_W     = (const float*)d_in[25];
  const float* out_b     = (const float*)d_in[26];
  float* out = (float*)d_out;

  float* ws     = (float*)d_ws;
  float* src_e  = ws;                        // [1024,512]
  float* dec_x0 = ws + 524288;               // [1024,512]
  float* x1     = ws + 1048576;              // [1024,512]
  float* x2     = ws + 1572864;              // [1024,512]
  float* xg_enc = ws + 2097152;              // [1024,4096]
  float* xg_d0  = xg_enc;                    // overlay: dec phase reuses enc xg
  float* xg_d1  = xg_enc + 2097152;
  float* spk0   = ws + 6291456;              // [1024,512]
  float* spk1   = ws + 6815744;              // [1024,512]
  float* st     = ws + 7340032;
  float* zbuf    = st;                       // [2048] zeros
  float* c0buf   = st + 2048;                // [2048]
  float* c1buf   = st + 4096;                // [2048]
  float* ring_e0 = st + 6144;                // [2][2048]
  float* ring_e1 = st + 10240;
  float* ring_d0 = st + 14336;
  float* ring_d1 = st + 18432;               // end st+22528

  zero_kernel<<<6, 256, 0, stream>>>(st, 1536);   // zbuf + c0 + c1
  embed_dyt<<<1024, 128, 0, stream>>>(src, emb_enc, enc_alpha, enc_gamma, enc_beta, src_e);
  embed_dyt<<<1024, 128, 0, stream>>>(tgt, emb_dec, dec_alpha, dec_gamma, dec_beta, dec_x0);

  // Encoder xg (both layers stacked [4096,512])
  gemm_nt<0><<<dim3(8, 32), 256, 0, stream>>>(src_e, enc_Wih, enc_bih, xg_enc, 4096, 512);

  // Encoder recurrence: 256 per-step dispatches, both layers each
  for (int t = 0; t < 256; ++t) {
    StepInst A, B;
    A.xg = xg_enc;        A.Whh = enc_Whh;            A.bhh = enc_bhh;
    A.c = c0buf;
    A.h_in  = (t == 0) ? zbuf : ring_e0 + (t & 1) * 2048;
    A.h_out = ring_e0 + ((t + 1) & 1) * 2048;
    A.xg_stride = 4096;
    B.xg = xg_enc + 2048; B.Whh = enc_Whh + 1048576;  B.bhh = enc_bhh + 2048;
    B.c = c1buf;
    B.h_in  = (t == 0) ? zbuf : ring_e1 + (t & 1) * 2048;
    B.h_out = ring_e1 + ((t + 1) & 1) * 2048;
    B.xg_stride = 4096;
    slstm_step<<<128, 256, 0, stream>>>(A, B, t);
  }
  // final enc h at ring_e{l} parity 0; final enc c in c{l}buf (continued in-place by dec)

  // Decoder layer0 xg (precomputed GEMM; overwrites xg_enc region)
  gemm_nt<0><<<dim3(8, 16), 256, 0, stream>>>(dec_x0, dec_Wih, dec_bih, xg_d0, 2048, 512);

  DecArgs D;
  D.xg0 = xg_d0;              D.xg1 = xg_d1;
  D.Whh0 = dec_Whh;           D.Whh1 = dec_Whh + 1048576;
  D.bhh0 = dec_bhh;           D.bhh1 = dec_bhh + 2048;
  D.Wih1 = dec_Wih + 1048576; D.bih1 = dec_bih + 2048;
  D.fc0W = dec_fc_W;          D.fc0b = dec_fc_b;
  D.fc1W = dec_fc_W + 262144; D.fc1b = dec_fc_b + 512;
  D.dyt_a = dyt_alpha;        D.dyt_g = dyt_gamma;     D.dyt_b = dyt_beta;
  D.thr0 = dec_thr;           D.thr1 = dec_thr + 512;
  D.c0 = c0buf;               D.c1 = c1buf;
  D.h0_init = ring_e0;        D.h1_init = ring_e1;     // parity-0 halves
  D.ring0 = ring_d0;          D.ring1 = ring_d1;
  D.spk0 = spk0;              D.spk1 = spk1;
  D.x1 = x1;                  D.x2 = x2;

  // 5-stage pipeline over 260 slots: A(t=s) B(t=s-1) C(t=s-2) D(t=s-3) E(t=s-4)
  for (int s = 0; s < 260; ++s)
    dec_slot<<<256, 256, 0, stream>>>(D, s);

  gemm_nt<0><<<dim3(8, 250), 256, 0, stream>>>(x2, out_W, out_b, out, 32000, 512);
}